// Round 4
// baseline (288.282 us; speedup 1.0000x reference)
//
#include <hip/hip_runtime.h>
#include <hip/hip_bf16.h>
#include <math.h>

// QRNN3D fused via bf16 MFMA implicit conv-GEMM + in-register fo-pool.
// GEMM per (b,h,t,wtile): D[32 gate-ch][32 pix] = sum over 27 taps of
//   A(tap)[32ch x 16c] * B(tap)[16c x 32pix],  A = weights in VGPRs (t-invariant),
//   B = im2col x-slice in this wave's PRIVATE LDS ring.
// C/D layout (32x32x16): col=lane&31=pixel, row=ch=(reg&3)+8*(reg>>2)+4*(lane>>5)
//   => z-gate ch in acc[r], f-gate ch+16 in acc[r+8], same lane: recurrence is
//   per-lane register math; stores coalesced (lane = pixel).
//
// BARRIER-FREE WAVE-PRIVATE PIPELINE (resubmit of R3; container flake, no data).
// R2 counters showed MfmaUtil+VALUBusy ~= 50%; other 50% = stalls, with both
// waves/SIMD phase-locked by the per-t __syncthreads. Now: grid 2048 x 64
// threads; each wave stages its own 40-column window (w0-4 .. w0+35,
// quad-aligned validity) into a private 4-slot LDS ring (15360 B).
// Producer->consumer ordering is within-wave program order (DS ops execute in
// issue order per wave; vmcnt covers globals): NO __syncthreads anywhere.
// Waves on a SIMD drift freely and fill each other's stall windows.
//
// LDS plane = [kh][c-octet][wpos 0..39][8c cell of 16B], cell-index XOR group
// swizzle swz(wp) = (wp&~7)|((wp^(wp>>3))&7):
// - MFMA B-reads: lanes read consecutive wp -> conflict-free.
// - Commits: lanes write wp at stride 4 -> swz spreads across bank groups.
// T14 split kept: plane t+2 loads ISSUED after commit of t+1, COMMITTED next
// iteration — full-iteration latency hiding.

namespace {
constexpr int kB = 4, kC = 16, kT = 31, kH = 128, kW = 128, kHid = 16;
constexpr int kHW  = kH * kW;
constexpr int kTHW = kT * kHW;
constexpr int kCell = 8;             // shorts per cell (8 c bf16 = 16B)
constexpr int kWp  = 40;             // wpos cells per (kh,oct) region
constexpr int kOS  = kWp * kCell;    // 320 shorts (640 B)
constexpr int kKS  = 2 * kOS;        // 640 shorts
constexpr int kPS  = 3 * kKS;        // 1920 shorts = 3840 B per plane
constexpr int kSlots = 4;            // ring: 15360 B total
}

typedef __attribute__((ext_vector_type(8)))  short  short8;
typedef __attribute__((ext_vector_type(4)))  float  floatv4;
typedef __attribute__((ext_vector_type(16))) float  floatx16;

__device__ __forceinline__ unsigned short f2bf(float f) {
    __hip_bfloat16 h = __float2bfloat16(f);   // RTN
    return __builtin_bit_cast(unsigned short, h);
}

// bank-group swizzle on the wpos cell index (bijective within 8-cell blocks)
__device__ __forceinline__ int swz(int wp) {
    return (wp & ~7) | ((wp ^ (wp >> 3)) & 7);
}

__global__ __launch_bounds__(64, 2) void qrnn_mfma(
    const float* __restrict__ x, const float* __restrict__ Wt,
    const float* __restrict__ bias, float* __restrict__ out)
{
    __shared__ unsigned short lds[kSlots * kPS];   // 15360 B, wave-private

    // XCD-aware decode: 256 consecutive work units per XCD -> adjacent h rows
    // (and the 4 w-tiles of each row) share staged x rows in the same L2.
    const int id   = blockIdx.x;                 // 0..2047
    const int orig = (id >> 3) + (id & 7) * 256;
    const int wt   = orig & 3;                   // w-tile (32 pixels each)
    const int bh   = orig >> 2;
    const int b    = bh >> 7;
    const int h    = bh & (kH - 1);
    const int w0   = wt * 32;

    const int lane = threadIdx.x;        // 0..63 (one wave)
    const int m    = lane & 31;          // A: gate channel ; B/D: pixel-in-tile
    const int hi   = lane >> 5;
    const int chi  = hi * 8;             // k-octet base (c dimension)

    const float* xb = x + b * (kC * kTHW);

    // ---- A-operand: all 27 tap fragments of W, bf16, in registers ----
    short8 wf[27];
#pragma unroll
    for (int tap = 0; tap < 27; ++tap) {
        short8 v;
#pragma unroll
        for (int j = 0; j < 8; ++j)
            v[j] = (short)f2bf(Wt[m * (kC * 27) + (chi + j) * 27 + tap]);
        wf[tap] = v;
    }

    // ---- per-lane recurrence state, biases, output offsets ----
    float st[8], zb[8], fbv[8];
    int ooff[8];
#pragma unroll
    for (int r = 0; r < 8; ++r) {
        const int hid = (r & 3) + 8 * (r >> 2) + 4 * hi;   // D-row for reg r
        zb[r]  = bias[hid];
        fbv[r] = bias[kHid + hid];
        st[r]  = 0.0f;
        ooff[r] = ((b * kHid + hid) * kT) * kHW + h * kW + w0 + m;
    }

    // ---- B-operand lane bases: kw=0/1/2 -> wpos m+3 / m+4 / m+5 ----
    // (window cell wp holds global w = w0 - 4 + wp; pixel P=w0+m reads
    //  w = P-1+kw -> wp = m+3+kw, range 3..36 < 40.)
    const unsigned short* bK0 = lds + hi * kOS + swz(m + 3) * kCell;
    const unsigned short* bK1 = lds + hi * kOS + swz(m + 4) * kCell;
    const unsigned short* bK2 = lds + hi * kOS + swz(m + 5) * kCell;

    // ---- wave-private staging: lane = (kh, w-quad 0..9, c-octet), 60 active ----
    const bool sact = lane < 60;
    const int  skh  = lane / 20;         // 0..2
    const int  srem = lane % 20;
    const int  sq   = srem >> 1;         // quad 0..9: w = w0-4+4*sq .. +3
    const int  soct = srem & 1;          // c-octet 0 or 8
    const int  wq0  = w0 - 4 + sq * 4;   // quad-aligned -> validity is per-quad
    const int  shr  = h + skh - 1;       // global row this lane stages
    const bool svalid = sact && wq0 >= 0 && wq0 < kW && shr >= 0 && shr < kH;
    const float* sbase = xb + (soct * 8) * kTHW + shr * kW + wq0;
    unsigned short* cb0 = lds + skh * kKS + soct * kOS;

    int cwoff[4];                        // swizzled commit cell offsets
#pragma unroll
    for (int i = 0; i < 4; ++i) cwoff[i] = swz(sq * 4 + i) * kCell;

    floatv4 sv[8];                       // staged: c = soct*8+j, w = quad elem i

    auto sissue = [&](int tp) {          // issue global loads for plane tp (no wait)
#pragma unroll
        for (int j = 0; j < 8; ++j) sv[j] = floatv4{0.f, 0.f, 0.f, 0.f};
        if (svalid && (unsigned)tp < (unsigned)kT) {
            const float* s = sbase + tp * kHW;
#pragma unroll
            for (int j = 0; j < 8; ++j)
                sv[j] = *(const floatv4*)(s + j * kTHW);
        }
    };
    auto scommit = [&](int tp) {         // cvt + write plane tp into its ring slot
        if (sact) {
            unsigned short* pl = cb0 + ((tp + 2 * kSlots) & (kSlots - 1)) * kPS;
#pragma unroll
            for (int i = 0; i < 4; ++i) {
                short8 v;
#pragma unroll
                for (int j = 0; j < 8; ++j) v[j] = (short)f2bf(sv[j][i]);
                *(short8*)(pl + cwoff[i]) = v;
            }
        }
    };

    // ---- prologue: plane -1 (zeros), plane 0 committed; plane 1 in flight ----
    sissue(-1); scommit(-1);
    sissue(0);  scommit(0);
    sissue(1);

    for (int t = 0; t < kT; ++t) {
        scommit(t + 1);                  // loads issued a full iteration ago
        sissue(t + 2);                   // in flight across compute(t) + epilogue

        floatx16 acc = {0,0,0,0,0,0,0,0,0,0,0,0,0,0,0,0};
#pragma unroll
        for (int kd = 0; kd < 3; ++kd) {
            const int soff = ((t + kd + 2 * kSlots - 1) & (kSlots - 1)) * kPS;
#pragma unroll
            for (int kh = 0; kh < 3; ++kh) {
                const int o = soff + kh * kKS;
                const short8 b0 = *(const short8*)(bK0 + o);   // kw=0 -> x[P-1]
                const short8 b1 = *(const short8*)(bK1 + o);   // kw=1 -> x[P]
                const short8 b2 = *(const short8*)(bK2 + o);   // kw=2 -> x[P+1]
                acc = __builtin_amdgcn_mfma_f32_32x32x16_bf16(wf[kd*9 + kh*3 + 0], b0, acc, 0, 0, 0);
                acc = __builtin_amdgcn_mfma_f32_32x32x16_bf16(wf[kd*9 + kh*3 + 1], b1, acc, 0, 0, 0);
                acc = __builtin_amdgcn_mfma_f32_32x32x16_bf16(wf[kd*9 + kh*3 + 2], b2, acc, 0, 0, 0);
            }
        }

        // epilogue: gates -> activations -> fo-pool -> coalesced store
#pragma unroll
        for (int r = 0; r < 8; ++r) {
            const float zp = acc[r]     + zb[r];
            const float fp = acc[r + 8] + fbv[r];
            const float e2 = __expf(2.0f * zp);
            const float z  = 1.0f - 2.0f * __builtin_amdgcn_rcpf(e2 + 1.0f);  // tanh(zp)
            const float f  = __builtin_amdgcn_rcpf(1.0f + __expf(-fp));       // sigmoid(fp)
            st[r] = z + f * (st[r] - z);
            out[ooff[r] + t * kHW] = st[r];
        }
    }
}

extern "C" void kernel_launch(void* const* d_in, const int* in_sizes, int n_in,
                              void* d_out, int out_size, void* d_ws, size_t ws_size,
                              hipStream_t stream) {
    const float* x    = (const float*)d_in[0];
    const float* Wt   = (const float*)d_in[1];
    const float* bias = (const float*)d_in[2];
    float* out = (float*)d_out;

    qrnn_mfma<<<dim3(kB * kH * 4), dim3(64), 0, stream>>>(x, Wt, bias, out);
}

// Round 5
// 260.741 us; speedup vs baseline: 1.1056x; 1.1056x over previous
//
#include <hip/hip_runtime.h>
#include <hip/hip_bf16.h>
#include <math.h>

// QRNN3D fused via bf16 MFMA implicit conv-GEMM + in-register fo-pool.
// GEMM per (b,h,t): D[32 gate-ch][128 pix] = sum over 27 taps of
//   A(tap)[32ch x 16c] * B(tap)[16c x 128pix],  A = weights in VGPRs (t-invariant),
//   B = im2col x-slice in LDS.
// C/D layout (32x32x16): col=lane&31=pixel, row=ch=(reg&3)+8*(reg>>2)+4*(lane>>5)
//   => z-gate ch in acc[r], f-gate ch+16 in acc[r+8], same lane: recurrence is
//   per-lane register math; stores coalesced (lane = pixel).
//
// Structure = R2 (103us): 512 blocks x 256 thr, 4-slot LDS ring, one
// __syncthreads per t, T14 issue/commit staging split.
//   (R4 experiment: barrier-free wave-private pipeline REGRESSED 103->132;
//    barrier is not the bottleneck — per-wave latency chains are.)
//
// THIS REVISION: 3 INDEPENDENT ACCUMULATOR CHAINS (ILP). Previously all 27
// MFMAs chained through one acc -> 27-deep dependent-latency chain that
// 2 waves/SIMD cannot hide. Now acc0/acc1/acc2 (one per kd), tap loop
// reordered kh-outer/kd-inner so consecutive MFMA triples round-robin the
// chains; summed in the epilogue. +32 VGPR — free (occupancy is grid-capped).
//
// LDS plane = [kh][c-octet][wpos][8c cell of 16B], cell-index XOR group
// swizzle swz(wp) = (wp&~7)|((wp^(wp>>3))&7):
// - MFMA B-reads: 8-lane clock groups read consecutive wp -> conflict-free.
// - Staged commits: lanes write wp at stride 4 -> swz spreads bank groups.

namespace {
constexpr int kB = 4, kC = 16, kT = 31, kH = 128, kW = 128, kHid = 16;
constexpr int kHW  = kH * kW;
constexpr int kTHW = kT * kHW;
constexpr int kCell = 8;             // shorts per cell (8 c bf16 = 16B)
constexpr int kOS  = 130 * kCell;    // c-octet region stride (shorts) = 1040
constexpr int kKS  = 2 * kOS;        // kh-row stride (shorts) = 2080
constexpr int kPS  = 3 * kKS;        // plane stride (shorts) = 6240 (12480 B)
constexpr int kSlots = 4;
}

typedef __attribute__((ext_vector_type(8)))  short  short8;
typedef __attribute__((ext_vector_type(4)))  float  floatv4;
typedef __attribute__((ext_vector_type(16))) float  floatx16;

__device__ __forceinline__ unsigned short f2bf(float f) {
    __hip_bfloat16 h = __float2bfloat16(f);   // RTN
    return __builtin_bit_cast(unsigned short, h);
}

// bank-group swizzle on the wpos cell index (bijective within 8-cell blocks)
__device__ __forceinline__ int swz(int wp) {
    return (wp & ~7) | ((wp ^ (wp >> 3)) & 7);
}

__global__ __launch_bounds__(256, 2) void qrnn_mfma(
    const float* __restrict__ x, const float* __restrict__ Wt,
    const float* __restrict__ bias, float* __restrict__ out)
{
    __shared__ unsigned short lds[kSlots * kPS];   // 49920 B

    // XCD-aware decode: 64 consecutive h per XCD -> staging rows L2-resident.
    const int id  = blockIdx.x;          // 0..511
    const int bh  = (id & 7) * 64 + (id >> 3);
    const int b   = bh >> 7;
    const int h   = bh & (kH - 1);

    const int tid  = threadIdx.x;
    const int lane = tid & 63;
    const int m    = lane & 31;          // A: gate channel ; B/D: pixel-in-tile
    const int hi   = lane >> 5;
    const int chi  = hi * 8;             // k-octet base (c dimension)
    const int n0   = (tid >> 6) * 32;    // wave's pixel tile base

    const float* xb = x + b * (kC * kTHW);

    // ---- A-operand: all 27 tap fragments of W, bf16, in registers ----
    short8 wf[27];
#pragma unroll
    for (int tap = 0; tap < 27; ++tap) {
        short8 v;
#pragma unroll
        for (int j = 0; j < 8; ++j)
            v[j] = (short)f2bf(Wt[m * (kC * 27) + (chi + j) * 27 + tap]);
        wf[tap] = v;
    }

    // ---- per-lane recurrence state, biases, output offsets ----
    float st[8], zb[8], fbv[8];
    int ooff[8];
    const int P = n0 + m;                // this lane's pixel (w coordinate)
#pragma unroll
    for (int r = 0; r < 8; ++r) {
        const int hid = (r & 3) + 8 * (r >> 2) + 4 * hi;   // D-row for reg r
        zb[r]  = bias[hid];
        fbv[r] = bias[kHid + hid];
        st[r]  = 0.0f;
        ooff[r] = ((b * kHid + hid) * kT) * kHW + h * kW + P;
    }

    // ---- B-operand lane base addresses: kw=0/1/2 -> wpos P / P+1 / P+2 ----
    const unsigned short* bK0 = lds + hi * kOS + swz(P)     * kCell;
    const unsigned short* bK1 = lds + hi * kOS + swz(P + 1) * kCell;
    const unsigned short* bK2 = lds + hi * kOS + swz(P + 2) * kCell;

    // ---- pipelined staging: thread = (kh, w-quad, c-octet), 192 active ----
    const bool sact = tid < 192;
    const int  skh  = tid >> 6;          // 0..2 for active threads (wave-uniform)
    const int  swq  = tid & 31;          // w-quad: covers w = swq*4 .. swq*4+3
    const int  soct = (tid >> 5) & 1;    // c-octet 0 or 8
    const int  shr  = h + skh - 1;       // global row this thread stages
    const bool srow = sact && (shr >= 0) && (shr < kH);   // wave-uniform
    const float* sbase = xb + (soct * 8) * kTHW + shr * kW + swq * 4;
    unsigned short* cb0 = lds + skh * kKS + soct * kOS;   // + slot*kPS + swz(wp)*kCell

    int cwoff[4];                        // swizzled commit cell offsets (const idx use)
#pragma unroll
    for (int q = 0; q < 4; ++q) cwoff[q] = swz(swq * 4 + q + 1) * kCell;

    floatv4 sv[8];                       // staged plane: c = soct*8+j, w = quad lane q

    auto sissue = [&](int tp) {          // issue global loads for plane tp (no wait)
#pragma unroll
        for (int j = 0; j < 8; ++j) sv[j] = floatv4{0.f, 0.f, 0.f, 0.f};
        if (srow && (unsigned)tp < (unsigned)kT) {    // wave-uniform branch
            const float* s = sbase + tp * kHW;
#pragma unroll
            for (int j = 0; j < 8; ++j)
                sv[j] = *(const floatv4*)(s + j * kTHW);
        }
    };
    auto scommit = [&](int tp) {         // cvt + write plane tp into its ring slot
        if (sact) {
            unsigned short* pl = cb0 + ((tp + 2 * kSlots) & (kSlots - 1)) * kPS;
#pragma unroll
            for (int q = 0; q < 4; ++q) {
                short8 v;
#pragma unroll
                for (int j = 0; j < 8; ++j) v[j] = (short)f2bf(sv[j][q]);
                *(short8*)(pl + cwoff[q]) = v;
            }
        }
    };

    // ---- halo cells (wpos 0 and 129) of all slots: zero once, never rewritten ----
    if (tid < 48) {   // 4 slots x 3 kh x 2 oct x 2 wp = 48 cells of 16B
        const int s = tid / 12, rem = tid % 12;
        const int khh = rem >> 2, q2 = rem & 3;
        const int oct = q2 >> 1;
        const int wp  = (q2 & 1) * 129;          // swz(0)=0, swz(129)=129
        const short8 z = {0, 0, 0, 0, 0, 0, 0, 0};
        *(short8*)(lds + s * kPS + khh * kKS + oct * kOS + swz(wp) * kCell) = z;
    }

    // ---- prologue: plane -1 (zeros) -> slot 3, plane 0 -> slot 0, plane 1 in regs ----
    sissue(-1); scommit(-1);
    sissue(0);  scommit(0);
    sissue(1);

    for (int t = 0; t < kT; ++t) {
        scommit(t + 1);                  // loads issued a full iteration ago
        __syncthreads();
        sissue(t + 2);                   // in flight across compute(t) + epilogue

        // slot byte offsets for kd = 0,1,2 -> planes t-1, t, t+1
        const int sA = ((t + 7) & (kSlots - 1)) * kPS;
        const int sB = ((t + 8) & (kSlots - 1)) * kPS;
        const int sC = ((t + 9) & (kSlots - 1)) * kPS;

        // 3 independent accumulator chains (one per kd); kh-outer order
        // round-robins the chains so MFMA dep latency is hidden by ILP.
        floatx16 acc0 = {0,0,0,0,0,0,0,0,0,0,0,0,0,0,0,0};
        floatx16 acc1 = {0,0,0,0,0,0,0,0,0,0,0,0,0,0,0,0};
        floatx16 acc2 = {0,0,0,0,0,0,0,0,0,0,0,0,0,0,0,0};
#pragma unroll
        for (int kh = 0; kh < 3; ++kh) {
            const int oA = sA + kh * kKS;
            const int oB = sB + kh * kKS;
            const int oC = sC + kh * kKS;
            {   // kd = 0 -> acc0
                const short8 b0 = *(const short8*)(bK0 + oA);
                const short8 b1 = *(const short8*)(bK1 + oA);
                const short8 b2 = *(const short8*)(bK2 + oA);
                acc0 = __builtin_amdgcn_mfma_f32_32x32x16_bf16(wf[kh*3 + 0], b0, acc0, 0, 0, 0);
                acc0 = __builtin_amdgcn_mfma_f32_32x32x16_bf16(wf[kh*3 + 1], b1, acc0, 0, 0, 0);
                acc0 = __builtin_amdgcn_mfma_f32_32x32x16_bf16(wf[kh*3 + 2], b2, acc0, 0, 0, 0);
            }
            {   // kd = 1 -> acc1
                const short8 b0 = *(const short8*)(bK0 + oB);
                const short8 b1 = *(const short8*)(bK1 + oB);
                const short8 b2 = *(const short8*)(bK2 + oB);
                acc1 = __builtin_amdgcn_mfma_f32_32x32x16_bf16(wf[9 + kh*3 + 0], b0, acc1, 0, 0, 0);
                acc1 = __builtin_amdgcn_mfma_f32_32x32x16_bf16(wf[9 + kh*3 + 1], b1, acc1, 0, 0, 0);
                acc1 = __builtin_amdgcn_mfma_f32_32x32x16_bf16(wf[9 + kh*3 + 2], b2, acc1, 0, 0, 0);
            }
            {   // kd = 2 -> acc2
                const short8 b0 = *(const short8*)(bK0 + oC);
                const short8 b1 = *(const short8*)(bK1 + oC);
                const short8 b2 = *(const short8*)(bK2 + oC);
                acc2 = __builtin_amdgcn_mfma_f32_32x32x16_bf16(wf[18 + kh*3 + 0], b0, acc2, 0, 0, 0);
                acc2 = __builtin_amdgcn_mfma_f32_32x32x16_bf16(wf[18 + kh*3 + 1], b1, acc2, 0, 0, 0);
                acc2 = __builtin_amdgcn_mfma_f32_32x32x16_bf16(wf[18 + kh*3 + 2], b2, acc2, 0, 0, 0);
            }
        }

        // epilogue: sum chains -> gates -> activations -> fo-pool -> store
#pragma unroll
        for (int r = 0; r < 8; ++r) {
            const float zp = acc0[r]     + acc1[r]     + acc2[r]     + zb[r];
            const float fp = acc0[r + 8] + acc1[r + 8] + acc2[r + 8] + fbv[r];
            const float e2 = __expf(2.0f * zp);
            const float z  = 1.0f - 2.0f * __builtin_amdgcn_rcpf(e2 + 1.0f);  // tanh(zp)
            const float f  = __builtin_amdgcn_rcpf(1.0f + __expf(-fp));       // sigmoid(fp)
            st[r] = z + f * (st[r] - z);
            out[ooff[r] + t * kHW] = st[r];
        }
    }
}

extern "C" void kernel_launch(void* const* d_in, const int* in_sizes, int n_in,
                              void* d_out, int out_size, void* d_ws, size_t ws_size,
                              hipStream_t stream) {
    const float* x    = (const float*)d_in[0];
    const float* Wt   = (const float*)d_in[1];
    const float* bias = (const float*)d_in[2];
    float* out = (float*)d_out;

    qrnn_mfma<<<dim3(kB * kH), dim3(256), 0, stream>>>(x, Wt, bias, out);
}

// Round 7
// 259.372 us; speedup vs baseline: 1.1115x; 1.0053x over previous
//
#include <hip/hip_runtime.h>
#include <hip/hip_bf16.h>
#include <math.h>

// QRNN3D fused via bf16 MFMA implicit conv-GEMM + in-register fo-pool.
// GEMM per (b,h,t): D[32 gate-ch][128 pix] = sum over 27 taps of
//   A(tap)[32ch x 16c] * B(tap)[16c x 128pix],  A = weights in VGPRs (t-invariant),
//   B = im2col x-slice in LDS.
// C/D layout (32x32x16): col=lane&31=pixel, row=ch=(reg&3)+8*(reg>>2)+4*(lane>>5)
//   => z-gate ch in acc[r], f-gate ch+16 in acc[r+8], same lane: recurrence is
//   per-lane register math; stores coalesced (lane = pixel).
//
// Structure = R2 (103us best): 512 blocks x 256 thr, 4-slot LDS ring, one
// barrier per t, T14 issue/commit staging split, single-acc kd-outer MFMA loop.
//   (R4: barrier-free wave-private pipeline REGRESSED -> barrier not the issue.
//    R5: 3 acc chains NEUTRAL -> MFMA dep latency already hidden.)
//
// THIS REVISION (resubmit of R6; container infra flake, no data): NO-VMCNT-
// DRAIN BARRIER. __syncthreads() makes the compiler emit s_waitcnt vmcnt(0)
// lgkmcnt(0) before s_barrier — forcing every wave to drain its 8 in-flight
// sissue() global loads EVERY iteration (exposed HBM latency, amplified by
// 4-wave skew). Correctness only needs the commit's ds_writes ordered before
// post-barrier ds_reads (ring slots are disjoint: commit at iter t writes
// slot (t+2)&3; compute reads (t-1..t+1)&3). So:
//     s_waitcnt lgkmcnt(0)  ;  s_barrier          (no vmcnt drain)
// Global loads stay in flight across barriers; the compiler inserts counted
// vmcnt waits only where scommit consumes sv. sissue moved before the barrier
// so loads issue during barrier wait. sched_barrier(0) + memory clobbers pin
// compute ds_reads behind the barrier (rule #18).
//
// LDS plane = [kh][c-octet][wpos][8c cell of 16B], cell-index XOR group
// swizzle swz(wp) = (wp&~7)|((wp^(wp>>3))&7):
// - MFMA B-reads: 8-lane clock groups read consecutive wp -> conflict-free.
// - Staged commits: lanes write wp at stride 4 -> swz spreads bank groups.

namespace {
constexpr int kB = 4, kC = 16, kT = 31, kH = 128, kW = 128, kHid = 16;
constexpr int kHW  = kH * kW;
constexpr int kTHW = kT * kHW;
constexpr int kCell = 8;             // shorts per cell (8 c bf16 = 16B)
constexpr int kOS  = 130 * kCell;    // c-octet region stride (shorts) = 1040
constexpr int kKS  = 2 * kOS;        // kh-row stride (shorts) = 2080
constexpr int kPS  = 3 * kKS;        // plane stride (shorts) = 6240 (12480 B)
constexpr int kSlots = 4;
}

typedef __attribute__((ext_vector_type(8)))  short  short8;
typedef __attribute__((ext_vector_type(4)))  float  floatv4;
typedef __attribute__((ext_vector_type(16))) float  floatx16;

__device__ __forceinline__ unsigned short f2bf(float f) {
    __hip_bfloat16 h = __float2bfloat16(f);   // RTN
    return __builtin_bit_cast(unsigned short, h);
}

// bank-group swizzle on the wpos cell index (bijective within 8-cell blocks)
__device__ __forceinline__ int swz(int wp) {
    return (wp & ~7) | ((wp ^ (wp >> 3)) & 7);
}

// Barrier that orders LDS writes -> LDS reads WITHOUT draining vmcnt.
__device__ __forceinline__ void lds_barrier() {
    asm volatile("s_waitcnt lgkmcnt(0)" ::: "memory");
    __builtin_amdgcn_s_barrier();
    asm volatile("" ::: "memory");
    __builtin_amdgcn_sched_barrier(0);
}

__global__ __launch_bounds__(256, 2) void qrnn_mfma(
    const float* __restrict__ x, const float* __restrict__ Wt,
    const float* __restrict__ bias, float* __restrict__ out)
{
    __shared__ unsigned short lds[kSlots * kPS];   // 49920 B

    // XCD-aware decode: 64 consecutive h per XCD -> staging rows L2-resident.
    const int id  = blockIdx.x;          // 0..511
    const int bh  = (id & 7) * 64 + (id >> 3);
    const int b   = bh >> 7;
    const int h   = bh & (kH - 1);

    const int tid  = threadIdx.x;
    const int lane = tid & 63;
    const int m    = lane & 31;          // A: gate channel ; B/D: pixel-in-tile
    const int hi   = lane >> 5;
    const int chi  = hi * 8;             // k-octet base (c dimension)
    const int n0   = (tid >> 6) * 32;    // wave's pixel tile base

    const float* xb = x + b * (kC * kTHW);

    // ---- A-operand: all 27 tap fragments of W, bf16, in registers ----
    short8 wf[27];
#pragma unroll
    for (int tap = 0; tap < 27; ++tap) {
        short8 v;
#pragma unroll
        for (int j = 0; j < 8; ++j)
            v[j] = (short)f2bf(Wt[m * (kC * 27) + (chi + j) * 27 + tap]);
        wf[tap] = v;
    }

    // ---- per-lane recurrence state, biases, output offsets ----
    float st[8], zb[8], fbv[8];
    int ooff[8];
    const int P = n0 + m;                // this lane's pixel (w coordinate)
#pragma unroll
    for (int r = 0; r < 8; ++r) {
        const int hid = (r & 3) + 8 * (r >> 2) + 4 * hi;   // D-row for reg r
        zb[r]  = bias[hid];
        fbv[r] = bias[kHid + hid];
        st[r]  = 0.0f;
        ooff[r] = ((b * kHid + hid) * kT) * kHW + h * kW + P;
    }

    // ---- B-operand lane base addresses: kw=0/1/2 -> wpos P / P+1 / P+2 ----
    const unsigned short* bK0 = lds + hi * kOS + swz(P)     * kCell;
    const unsigned short* bK1 = lds + hi * kOS + swz(P + 1) * kCell;
    const unsigned short* bK2 = lds + hi * kOS + swz(P + 2) * kCell;

    // ---- pipelined staging: thread = (kh, w-quad, c-octet), 192 active ----
    const bool sact = tid < 192;
    const int  skh  = tid >> 6;          // 0..2 for active threads (wave-uniform)
    const int  swq  = tid & 31;          // w-quad: covers w = swq*4 .. swq*4+3
    const int  soct = (tid >> 5) & 1;    // c-octet 0 or 8
    const int  shr  = h + skh - 1;       // global row this thread stages
    const bool srow = sact && (shr >= 0) && (shr < kH);   // wave-uniform
    const float* sbase = xb + (soct * 8) * kTHW + shr * kW + swq * 4;
    unsigned short* cb0 = lds + skh * kKS + soct * kOS;   // + slot*kPS + swz(wp)*kCell

    int cwoff[4];                        // swizzled commit cell offsets (const idx use)
#pragma unroll
    for (int q = 0; q < 4; ++q) cwoff[q] = swz(swq * 4 + q + 1) * kCell;

    floatv4 sv[8];                       // staged plane: c = soct*8+j, w = quad lane q

    auto sissue = [&](int tp) {          // issue global loads for plane tp (no wait)
#pragma unroll
        for (int j = 0; j < 8; ++j) sv[j] = floatv4{0.f, 0.f, 0.f, 0.f};
        if (srow && (unsigned)tp < (unsigned)kT) {    // wave-uniform branch
            const float* s = sbase + tp * kHW;
#pragma unroll
            for (int j = 0; j < 8; ++j)
                sv[j] = *(const floatv4*)(s + j * kTHW);
        }
    };
    auto scommit = [&](int tp) {         // cvt + write plane tp into its ring slot
        if (sact) {
            unsigned short* pl = cb0 + ((tp + 2 * kSlots) & (kSlots - 1)) * kPS;
#pragma unroll
            for (int q = 0; q < 4; ++q) {
                short8 v;
#pragma unroll
                for (int j = 0; j < 8; ++j) v[j] = (short)f2bf(sv[j][q]);
                *(short8*)(pl + cwoff[q]) = v;
            }
        }
    };

    // ---- halo cells (wpos 0 and 129) of all slots: zero once, never rewritten ----
    if (tid < 48) {   // 4 slots x 3 kh x 2 oct x 2 wp = 48 cells of 16B
        const int s = tid / 12, rem = tid % 12;
        const int khh = rem >> 2, q2 = rem & 3;
        const int oct = q2 >> 1;
        const int wp  = (q2 & 1) * 129;          // swz(0)=0, swz(129)=129
        const short8 z = {0, 0, 0, 0, 0, 0, 0, 0};
        *(short8*)(lds + s * kPS + khh * kKS + oct * kOS + swz(wp) * kCell) = z;
    }

    // ---- prologue: plane -1 (zeros) -> slot 3, plane 0 -> slot 0, plane 1 in regs ----
    sissue(-1); scommit(-1);
    sissue(0);  scommit(0);
    sissue(1);

    for (int t = 0; t < kT; ++t) {
        scommit(t + 1);                  // loads issued a full iteration ago
        sissue(t + 2);                   // in flight across barrier + compute(t)
        lds_barrier();                   // lgkmcnt(0) + s_barrier — NO vmcnt drain

        floatx16 acc = {0,0,0,0,0,0,0,0,0,0,0,0,0,0,0,0};
#pragma unroll
        for (int kd = 0; kd < 3; ++kd) {
            const int soff = ((t + kd + 2 * kSlots - 1) & (kSlots - 1)) * kPS;
#pragma unroll
            for (int kh = 0; kh < 3; ++kh) {
                const int o = soff + kh * kKS;
                const short8 b0 = *(const short8*)(bK0 + o);   // kw=0 -> x[P-1]
                const short8 b1 = *(const short8*)(bK1 + o);   // kw=1 -> x[P]
                const short8 b2 = *(const short8*)(bK2 + o);   // kw=2 -> x[P+1]
                acc = __builtin_amdgcn_mfma_f32_32x32x16_bf16(wf[kd*9 + kh*3 + 0], b0, acc, 0, 0, 0);
                acc = __builtin_amdgcn_mfma_f32_32x32x16_bf16(wf[kd*9 + kh*3 + 1], b1, acc, 0, 0, 0);
                acc = __builtin_amdgcn_mfma_f32_32x32x16_bf16(wf[kd*9 + kh*3 + 2], b2, acc, 0, 0, 0);
            }
        }

        // epilogue: gates -> activations -> fo-pool -> coalesced store
#pragma unroll
        for (int r = 0; r < 8; ++r) {
            const float zp = acc[r]     + zb[r];
            const float fp = acc[r + 8] + fbv[r];
            const float e2 = __expf(2.0f * zp);
            const float z  = 1.0f - 2.0f * __builtin_amdgcn_rcpf(e2 + 1.0f);  // tanh(zp)
            const float f  = __builtin_amdgcn_rcpf(1.0f + __expf(-fp));       // sigmoid(fp)
            st[r] = z + f * (st[r] - z);
            out[ooff[r] + t * kHW] = st[r];
        }
    }
}

extern "C" void kernel_launch(void* const* d_in, const int* in_sizes, int n_in,
                              void* d_out, int out_size, void* d_ws, size_t ws_size,
                              hipStream_t stream) {
    const float* x    = (const float*)d_in[0];
    const float* Wt   = (const float*)d_in[1];
    const float* bias = (const float*)d_in[2];
    float* out = (float*)d_out;

    qrnn_mfma<<<dim3(kB * kH), dim3(256), 0, stream>>>(x, Wt, bias, out);
}